// Round 9
// baseline (413.496 us; speedup 1.0000x reference)
//
#include <hip/hip_runtime.h>

typedef __attribute__((ext_vector_type(8))) __bf16 bf16x8;
typedef __attribute__((ext_vector_type(4))) float f32x4;

constexpr int T  = 4096;   // tokens
constexpr int Dm = 1024;   // model dim
constexpr int Hm = 4096;   // hidden dim
constexpr int NE = 8;      // experts
constexpr int CAP = 1075;  // capacity  round(2*4096*1.05/8)
constexpr int CP  = 1152;  // capacity padded to 9*128

static __device__ __forceinline__ unsigned short f2bf(float f) {
  unsigned int u = __float_as_uint(f);
  u += 0x7FFFu + ((u >> 16) & 1u);   // RNE
  return (unsigned short)(u >> 16);
}
static __device__ __forceinline__ float bf2f(unsigned short u) {
  return __uint_as_float(((unsigned int)u) << 16);
}

static __device__ __forceinline__ void gload_lds16(const void* g, void* l) {
  __builtin_amdgcn_global_load_lds(
      (const __attribute__((address_space(1))) void*)g,
      (__attribute__((address_space(3))) void*)l, 16, 0, 0);
}

// ---------------- device bodies ----------------

// transpose+convert one 64(k) x 32(n) tile: W [Kd][N] f32 -> Wt [N][Kd] bf16
static __device__ __forceinline__ void transpose_body(
    float (*tile)[33], const float* __restrict__ W, unsigned short* __restrict__ Wt,
    int Kd, int N, int e, int n0, int k0) {
  const float* src = W + ((long long)e * Kd + k0) * N + n0;
  const int tid = threadIdx.x;
  const int r = tid >> 3;            // 0..31
  const int c4 = (tid & 7) * 4;
#pragma unroll
  for (int hh = 0; hh < 2; ++hh) {
    float4 v = *(const float4*)(src + (long long)(r + 32 * hh) * N + c4);
    tile[r + 32 * hh][c4] = v.x; tile[r + 32 * hh][c4 + 1] = v.y;
    tile[r + 32 * hh][c4 + 2] = v.z; tile[r + 32 * hh][c4 + 3] = v.w;
  }
  __syncthreads();
  const int n = tid >> 4;            // 0..15
  const int k4 = (tid & 15) * 4;
  unsigned short* dst = Wt + ((long long)e * N + n0) * Kd + k0;
#pragma unroll
  for (int hh = 0; hh < 2; ++hh) {
    int nn = n + 16 * hh;
    ushort4 o;
    o.x = f2bf(tile[k4][nn]);     o.y = f2bf(tile[k4 + 1][nn]);
    o.z = f2bf(tile[k4 + 2][nn]); o.w = f2bf(tile[k4 + 3][nn]);
    *(ushort4*)(dst + (long long)nn * Kd + k4) = o;
  }
}

// router body for token group (4 tokens per block of 256 threads)
static __device__ __forceinline__ void router_body(
    const float* __restrict__ x, const float* __restrict__ Wg,
    int* __restrict__ topi, float* __restrict__ topw, int blk) {
  int t = blk * 4 + (threadIdx.x >> 6);
  int lane = threadIdx.x & 63;
  const float* xr = x + (size_t)t * Dm;
  float acc[NE];
#pragma unroll
  for (int e = 0; e < NE; ++e) acc[e] = 0.f;
  for (int i = lane * 4; i < Dm; i += 256) {
    float4 xv = *(const float4*)(xr + i);
#pragma unroll
    for (int e = 0; e < NE; ++e) {
      float4 wv = *(const float4*)(Wg + e * Dm + i);
      acc[e] += xv.x * wv.x + xv.y * wv.y + xv.z * wv.z + xv.w * wv.w;
    }
  }
#pragma unroll
  for (int off = 32; off > 0; off >>= 1) {
#pragma unroll
    for (int e = 0; e < NE; ++e) acc[e] += __shfl_xor(acc[e], off, 64);
  }
  if (lane == 0) {
    float mx = acc[0];
#pragma unroll
    for (int e = 1; e < NE; ++e) mx = fmaxf(mx, acc[e]);
    float g[NE];
    float s = 0.f;
#pragma unroll
    for (int e = 0; e < NE; ++e) { g[e] = expf(acc[e] - mx); s += g[e]; }
    int i0 = 0; float v0 = g[0];
#pragma unroll
    for (int e = 1; e < NE; ++e) if (g[e] > v0) { v0 = g[e]; i0 = e; }
    int i1 = -1; float v1 = -1e30f;
#pragma unroll
    for (int e = 0; e < NE; ++e) {
      if (e == i0) continue;
      if (g[e] > v1) { v1 = g[e]; i1 = e; }
    }
    float inv = 1.f / s;
    topi[t * 2] = i0; topi[t * 2 + 1] = i1;
    topw[t * 2] = v0 * inv; topw[t * 2 + 1] = v1 * inv;
  }
}

// single-buffered K-loop (proven m97 structure): recompute addresses per kt,
// let the compiler fold offsets / schedule waitcnts (hoisting regressed, r8).
static __device__ __forceinline__ void gemm_mainloop(
    unsigned short* Alds, unsigned short* Blds,
    const unsigned short* __restrict__ Ab, const unsigned short* __restrict__ Btb,
    int Kd, f32x4 (&acc)[4][4]) {
  const int tid = threadIdx.x;
  const int lane = tid & 63;
  const int wid = tid >> 6;
  const int wr = (wid >> 1) * 64;
  const int wc = (wid & 1) * 64;
  const int l15 = lane & 15;
  const int khi = lane >> 4;
  const int swz = lane & 7;
  const int srow = lane >> 3;
  const int sslot = (lane & 7) ^ srow;

  const int nK = Kd >> 6;
  for (int kt = 0; kt < nK; ++kt) {
    const int kb = kt << 6;
#pragma unroll
    for (int j = 0; j < 4; ++j) {
      const int c = wid * 4 + j;
      const long long rowg = 8 * c + srow;
      gload_lds16(Ab  + rowg * Kd + kb + sslot * 8, &Alds[c * 512]);
      gload_lds16(Btb + rowg * Kd + kb + sslot * 8, &Blds[c * 512]);
    }
    __syncthreads();
#pragma unroll
    for (int kk = 0; kk < 2; ++kk) {
      bf16x8 af[4], bfv[4];
#pragma unroll
      for (int m = 0; m < 4; ++m)
        af[m] = *(const bf16x8*)&Alds[(wr + m * 16 + l15) * 64 + (((kk * 4 + khi) ^ swz) << 3)];
#pragma unroll
      for (int n = 0; n < 4; ++n)
        bfv[n] = *(const bf16x8*)&Blds[(wc + n * 16 + l15) * 64 + (((kk * 4 + khi) ^ swz) << 3)];
#pragma unroll
      for (int m = 0; m < 4; ++m)
#pragma unroll
        for (int n = 0; n < 4; ++n)
          acc[m][n] = __builtin_amdgcn_mfma_f32_16x16x32_bf16(af[m], bfv[n], acc[m][n], 0, 0, 0);
    }
    __syncthreads();
  }
}

// ---------------- kernels ----------------

// fused pre-pass block order: router, W2 tiles, W1 tiles LAST (W1t hot in L2/L3).
__global__ __launch_bounds__(256) void fused_pre_kernel(
    const float* __restrict__ x, const float* __restrict__ Wg,
    int* __restrict__ topi, float* __restrict__ topw,
    const float* __restrict__ W1, unsigned short* __restrict__ W1t,
    const float* __restrict__ W2, unsigned short* __restrict__ W2t,
    int nR, int nT2) {
  __shared__ __align__(16) float tile[64][33];
  const int bid = blockIdx.x;
  if (bid < nR) {
    router_body(x, Wg, topi, topw, bid);
  } else if (bid < nR + nT2) {
    // W2: Kd=Hm, N=Dm; layout (Dm/32) x (Hm/64) x NE
    int tb = bid - nR;
    int nb = tb % (Dm / 32);
    int rest = tb / (Dm / 32);
    int kb = rest % (Hm / 64);
    int e = rest / (Hm / 64);
    transpose_body(tile, W2, W2t, Hm, Dm, e, nb * 32, kb * 64);
  } else {
    // W1: Kd=Dm, N=Hm; layout (Hm/32) x (Dm/64) x NE
    int tb = bid - nR - nT2;
    int nb = tb % (Hm / 32);
    int rest = tb / (Hm / 32);
    int kb = rest % (Dm / 64);
    int e = rest / (Dm / 64);
    transpose_body(tile, W1, W1t, Dm, Hm, e, nb * 32, kb * 64);
  }
}

// dispatch: parallel slot-major multi-counter prefix scan (1 block x 1024)
__global__ __launch_bounds__(1024) void dispatch_scan_kernel(
    const int* __restrict__ topi, int* __restrict__ pos, int* __restrict__ within,
    int* __restrict__ cnt) {
  __shared__ unsigned long long sc0[1024];
  __shared__ unsigned long long sc1[1024];
  const int tid = threadIdx.x;
  int myE[8];
  unsigned long long w0 = 0, w1 = 0;
#pragma unroll
  for (int j = 0; j < 8; ++j) {
    int a = tid * 8 + j;
    int k = a >> 12;
    int t = a & (T - 1);
    int e = topi[t * 2 + k];
    myE[j] = e;
    unsigned long long inc = 1ULL << (16 * (e & 3));
    if (e < 4) w0 += inc; else w1 += inc;
  }
  const unsigned long long l0 = w0, l1 = w1;
  sc0[tid] = w0; sc1[tid] = w1;
  __syncthreads();
  for (int off = 1; off < 1024; off <<= 1) {
    unsigned long long a0 = 0, a1 = 0;
    if (tid >= off) { a0 = sc0[tid - off]; a1 = sc1[tid - off]; }
    __syncthreads();
    w0 += a0; w1 += a1;
    sc0[tid] = w0; sc1[tid] = w1;
    __syncthreads();
  }
  if (tid == 1023) {
#pragma unroll
    for (int e = 0; e < 4; ++e) {
      cnt[e]     = (int)((w0 >> (16 * e)) & 0xFFFF);
      cnt[e + 4] = (int)((w1 >> (16 * e)) & 0xFFFF);
    }
  }
  unsigned long long e0 = w0 - l0, e1 = w1 - l1;
#pragma unroll
  for (int j = 0; j < 8; ++j) {
    int a = tid * 8 + j;
    int e = myE[j];
    int sh = 16 * (e & 3);
    int p;
    if (e < 4) { p = (int)((e0 >> sh) & 0xFFFF); e0 += 1ULL << sh; }
    else       { p = (int)((e1 >> sh) & 0xFFFF); e1 += 1ULL << sh; }
    pos[a] = p;
    within[a] = (p < CAP) ? 1 : 0;
  }
}

// scatter accepted tokens -> buf[e][p] (bf16)
__global__ __launch_bounds__(256) void scatter_kernel(
    const float* __restrict__ x, const int* __restrict__ topi,
    const int* __restrict__ pos, const int* __restrict__ within,
    unsigned short* __restrict__ buf) {
  int a = blockIdx.x;
  if (!within[a]) return;
  int k = a >> 12, t = a & (T - 1);
  int e = topi[t * 2 + k];
  int p = pos[a];
  const float* src = x + (size_t)t * Dm;
  unsigned short* dst = buf + ((size_t)e * CP + p) * Dm;
  int i = threadIdx.x * 4;
  float4 v = *(const float4*)(src + i);
  ushort4 o;
  o.x = f2bf(v.x); o.y = f2bf(v.y); o.z = f2bf(v.z); o.w = f2bf(v.w);
  *(ushort4*)(dst + i) = o;
}

// GEMM1: h = gelu(buf @ W1t^T + b1)  [bf16 out], early-exit on expert count
__global__ __launch_bounds__(256) void gemm1_kernel(
    const unsigned short* __restrict__ buf, const unsigned short* __restrict__ W1t,
    const float* __restrict__ b1, unsigned short* __restrict__ h,
    const int* __restrict__ cnt) {
  __shared__ __align__(16) unsigned short Alds[128 * 64];
  __shared__ __align__(16) unsigned short Blds[128 * 64];
  const int e = blockIdx.x & 7;
  const int q = blockIdx.x >> 3;
  const int mb = q % (CP / 128);
  const int nb = q / (CP / 128);
  const int ce = min(cnt[e], CAP);
  if (mb * 128 >= ce) return;

  f32x4 acc[4][4];
#pragma unroll
  for (int m = 0; m < 4; ++m)
#pragma unroll
    for (int n = 0; n < 4; ++n) acc[m][n] = (f32x4){0.f, 0.f, 0.f, 0.f};

  gemm_mainloop(Alds, Blds,
                buf + ((long long)e * CP + mb * 128) * Dm,
                W1t + ((long long)e * Hm + nb * 128) * Dm, Dm, acc);

  const int lane = threadIdx.x & 63;
  const int wid = threadIdx.x >> 6;
  const int wr = (wid >> 1) * 64;
  const int wc = (wid & 1) * 64;
  const int l15 = lane & 15;
  const int crow = (lane >> 4) * 4;
  const float* bias = b1 + (size_t)e * Hm;
  unsigned short* H = h + (size_t)e * CP * Hm;
#pragma unroll
  for (int m = 0; m < 4; ++m) {
#pragma unroll
    for (int n = 0; n < 4; ++n) {
      const long long col = (long long)nb * 128 + wc + n * 16 + l15;
      const float bvv = bias[col];
#pragma unroll
      for (int j = 0; j < 4; ++j) {
        const long long row = (long long)mb * 128 + wr + m * 16 + crow + j;
        float v = acc[m][n][j] + bvv;
        v = 0.5f * v * (1.f + erff(v * 0.70710678118654752f));
        H[row * Hm + col] = f2bf(v);
      }
    }
  }
}

// GEMM2: y = h @ W2t^T + b2  [bf16 out], early-exit on expert count
__global__ __launch_bounds__(256) void gemm2_kernel(
    const unsigned short* __restrict__ h, const unsigned short* __restrict__ W2t,
    const float* __restrict__ b2, unsigned short* __restrict__ y,
    const int* __restrict__ cnt) {
  __shared__ __align__(16) unsigned short Alds[128 * 64];
  __shared__ __align__(16) unsigned short Blds[128 * 64];
  const int e = blockIdx.x & 7;
  const int q = blockIdx.x >> 3;
  const int mb = q % (CP / 128);
  const int nb = q / (CP / 128);
  const int ce = min(cnt[e], CAP);
  if (mb * 128 >= ce) return;

  f32x4 acc[4][4];
#pragma unroll
  for (int m = 0; m < 4; ++m)
#pragma unroll
    for (int n = 0; n < 4; ++n) acc[m][n] = (f32x4){0.f, 0.f, 0.f, 0.f};

  gemm_mainloop(Alds, Blds,
                h + ((long long)e * CP + mb * 128) * Hm,
                W2t + ((long long)e * Dm + nb * 128) * Hm, Hm, acc);

  const int lane = threadIdx.x & 63;
  const int wid = threadIdx.x >> 6;
  const int wr = (wid >> 1) * 64;
  const int wc = (wid & 1) * 64;
  const int l15 = lane & 15;
  const int crow = (lane >> 4) * 4;
  const float* bias = b2 + (size_t)e * Dm;
  unsigned short* Y = y + (size_t)e * CP * Dm;
#pragma unroll
  for (int m = 0; m < 4; ++m) {
#pragma unroll
    for (int n = 0; n < 4; ++n) {
      const long long col = (long long)nb * 128 + wc + n * 16 + l15;
      const float bvv = bias[col];
#pragma unroll
      for (int j = 0; j < 4; ++j) {
        const long long row = (long long)mb * 128 + wr + m * 16 + crow + j;
        Y[row * Dm + col] = f2bf(acc[m][n][j] + bvv);
      }
    }
  }
}

// combine: out[t] = sum_k w_k * y[e_k, p_k]   (y bf16)
__global__ __launch_bounds__(256) void combine_kernel(
    const unsigned short* __restrict__ y, const int* __restrict__ topi,
    const float* __restrict__ topw, const int* __restrict__ pos,
    const int* __restrict__ within, float* __restrict__ out) {
  int t = blockIdx.x;
  int i = threadIdx.x * 4;
  float4 r = {0.f, 0.f, 0.f, 0.f};
#pragma unroll
  for (int k = 0; k < 2; ++k) {
    int a = k * T + t;
    if (within[a]) {
      int e = topi[t * 2 + k];
      int p = pos[a];
      float w = topw[t * 2 + k];
      const unsigned short* yr = y + ((size_t)e * CP + p) * Dm + i;
      ushort4 v = *(const ushort4*)yr;
      r.x += w * bf2f(v.x); r.y += w * bf2f(v.y);
      r.z += w * bf2f(v.z); r.w += w * bf2f(v.w);
    }
  }
  *(float4*)(out + (size_t)t * Dm + i) = r;
}

// plain transpose (tight-memory fallback)
__global__ __launch_bounds__(256) void transpose_kernel(
    const float* __restrict__ W, unsigned short* __restrict__ Wt, int Kd, int N) {
  __shared__ __align__(16) float tile[64][33];
  transpose_body(tile, W, Wt, Kd, N, blockIdx.z, blockIdx.x * 32, blockIdx.y * 64);
}

extern "C" void kernel_launch(void* const* d_in, const int* in_sizes, int n_in,
                              void* d_out, int out_size, void* d_ws, size_t ws_size,
                              hipStream_t stream) {
  const float* x  = (const float*)d_in[0];
  const float* Wg = (const float*)d_in[1];
  const float* W1 = (const float*)d_in[2];
  const float* b1 = (const float*)d_in[3];
  const float* W2 = (const float*)d_in[4];
  const float* b2 = (const float*)d_in[5];
  float* out = (float*)d_out;

  char* ws = (char*)d_ws;
  const size_t sz_h   = (size_t)NE * CP * Hm * 2;   // 75.5 MB
  const size_t sz_buf = (size_t)NE * CP * Dm * 2;   // 18.9 MB (buf; later y bf16)
  const size_t sz_w   = (size_t)NE * Hm * Dm * 2;   // 67.1 MB
  const size_t sz_small = (size_t)2 * T * 4 * 4 + 64;
  const size_t need_full = sz_h + sz_buf + 2 * sz_w + sz_small;  // ~229 MB (ws>=247 proven, round 4)

  unsigned short* h   = (unsigned short*)ws;
  unsigned short* buf = (unsigned short*)(ws + sz_h);   // bf16 [E][CP][Dm]
  unsigned short* y   = buf;                            // bf16 y overwrites buf
  unsigned short* W1t = (unsigned short*)(ws + sz_h + sz_buf);
  const bool full = (ws_size >= need_full);
  unsigned short* W2t = full ? (W1t + sz_w / 2) : W1t;  // mid: shared slot
  char* smallp = ws + sz_h + sz_buf + (full ? 2 * sz_w : sz_w);
  int*   topi   = (int*)smallp;
  float* topw   = (float*)(topi + 2 * T);
  int*   pos    = (int*)(topw + 2 * T);
  int*   within = pos + 2 * T;
  int*   cnt    = within + 2 * T;

  const int nM = CP / 128;                    // 9
  const int nR = T / 4;                       // 1024 router blocks
  const int nT = (Hm / 32) * (Dm / 64) * NE;  // 16384 tiles per weight matrix
  const int nGemm1 = NE * nM * (Hm / 128);    // 2304
  const int nGemm2 = NE * nM * (Dm / 128);    // 576

  if (full) {
    // router + W2t + W1t(last) in one BW-bound pre-pass
    fused_pre_kernel<<<nR + 2 * nT, 256, 0, stream>>>(
        x, Wg, topi, topw, W1, W1t, W2, W2t, nR, nT);
    dispatch_scan_kernel<<<1, 1024, 0, stream>>>(topi, pos, within, cnt);
    scatter_kernel<<<2 * T, 256, 0, stream>>>(x, topi, pos, within, buf);
    gemm1_kernel<<<nGemm1, 256, 0, stream>>>(buf, W1t, b1, h, cnt);
    gemm2_kernel<<<nGemm2, 256, 0, stream>>>(h, W2t, b2, y, cnt);
  } else {
    // mid path: W1t in pre-pass, W2t after GEMM1 (same slot)
    fused_pre_kernel<<<nR + nT, 256, 0, stream>>>(
        x, Wg, topi, topw, W1, W1t, W2, W2t, nR, 0);
    dispatch_scan_kernel<<<1, 1024, 0, stream>>>(topi, pos, within, cnt);
    scatter_kernel<<<2 * T, 256, 0, stream>>>(x, topi, pos, within, buf);
    gemm1_kernel<<<nGemm1, 256, 0, stream>>>(buf, W1t, b1, h, cnt);
    transpose_kernel<<<dim3(Dm / 32, Hm / 64, NE), 256, 0, stream>>>(W2, W2t, Hm, Dm);
    gemm2_kernel<<<nGemm2, 256, 0, stream>>>(h, W2t, b2, y, cnt);
  }

  combine_kernel<<<T, 256, 0, stream>>>(y, topi, topw, pos, within, out);
}

// Round 10
// 343.094 us; speedup vs baseline: 1.2052x; 1.2052x over previous
//
#include <hip/hip_runtime.h>

typedef __attribute__((ext_vector_type(8))) __bf16 bf16x8;
typedef __attribute__((ext_vector_type(4))) float f32x4;

constexpr int T  = 4096;   // tokens
constexpr int Dm = 1024;   // model dim
constexpr int Hm = 4096;   // hidden dim
constexpr int NE = 8;      // experts
constexpr int CAP = 1075;  // capacity  round(2*4096*1.05/8)
constexpr int CP  = 1152;  // capacity padded to 9*128

static __device__ __forceinline__ unsigned short f2bf(float f) {
  unsigned int u = __float_as_uint(f);
  u += 0x7FFFu + ((u >> 16) & 1u);   // RNE
  return (unsigned short)(u >> 16);
}
static __device__ __forceinline__ float bf2f(unsigned short u) {
  return __uint_as_float(((unsigned int)u) << 16);
}

static __device__ __forceinline__ void gload_lds16(const void* g, void* l) {
  __builtin_amdgcn_global_load_lds(
      (const __attribute__((address_space(1))) void*)g,
      (__attribute__((address_space(3))) void*)l, 16, 0, 0);
}

// ---------------- device bodies ----------------

// transpose+convert one 64(k) x 32(n) tile: W [Kd][N] f32 -> Wt [N][Kd] bf16
static __device__ __forceinline__ void transpose_body(
    float (*tile)[33], const float* __restrict__ W, unsigned short* __restrict__ Wt,
    int Kd, int N, int e, int n0, int k0) {
  const float* src = W + ((long long)e * Kd + k0) * N + n0;
  const int tid = threadIdx.x;
  const int r = tid >> 3;            // 0..31
  const int c4 = (tid & 7) * 4;
#pragma unroll
  for (int hh = 0; hh < 2; ++hh) {
    float4 v = *(const float4*)(src + (long long)(r + 32 * hh) * N + c4);
    tile[r + 32 * hh][c4] = v.x; tile[r + 32 * hh][c4 + 1] = v.y;
    tile[r + 32 * hh][c4 + 2] = v.z; tile[r + 32 * hh][c4 + 3] = v.w;
  }
  __syncthreads();
  const int n = tid >> 4;            // 0..15
  const int k4 = (tid & 15) * 4;
  unsigned short* dst = Wt + ((long long)e * N + n0) * Kd + k0;
#pragma unroll
  for (int hh = 0; hh < 2; ++hh) {
    int nn = n + 16 * hh;
    ushort4 o;
    o.x = f2bf(tile[k4][nn]);     o.y = f2bf(tile[k4 + 1][nn]);
    o.z = f2bf(tile[k4 + 2][nn]); o.w = f2bf(tile[k4 + 3][nn]);
    *(ushort4*)(dst + (long long)nn * Kd + k4) = o;
  }
}

// router body for token group (4 tokens per block of 256 threads)
static __device__ __forceinline__ void router_body(
    const float* __restrict__ x, const float* __restrict__ Wg,
    int* __restrict__ topi, float* __restrict__ topw, int blk) {
  int t = blk * 4 + (threadIdx.x >> 6);
  int lane = threadIdx.x & 63;
  const float* xr = x + (size_t)t * Dm;
  float acc[NE];
#pragma unroll
  for (int e = 0; e < NE; ++e) acc[e] = 0.f;
  for (int i = lane * 4; i < Dm; i += 256) {
    float4 xv = *(const float4*)(xr + i);
#pragma unroll
    for (int e = 0; e < NE; ++e) {
      float4 wv = *(const float4*)(Wg + e * Dm + i);
      acc[e] += xv.x * wv.x + xv.y * wv.y + xv.z * wv.z + xv.w * wv.w;
    }
  }
#pragma unroll
  for (int off = 32; off > 0; off >>= 1) {
#pragma unroll
    for (int e = 0; e < NE; ++e) acc[e] += __shfl_xor(acc[e], off, 64);
  }
  if (lane == 0) {
    float mx = acc[0];
#pragma unroll
    for (int e = 1; e < NE; ++e) mx = fmaxf(mx, acc[e]);
    float g[NE];
    float s = 0.f;
#pragma unroll
    for (int e = 0; e < NE; ++e) { g[e] = expf(acc[e] - mx); s += g[e]; }
    int i0 = 0; float v0 = g[0];
#pragma unroll
    for (int e = 1; e < NE; ++e) if (g[e] > v0) { v0 = g[e]; i0 = e; }
    int i1 = -1; float v1 = -1e30f;
#pragma unroll
    for (int e = 0; e < NE; ++e) {
      if (e == i0) continue;
      if (g[e] > v1) { v1 = g[e]; i1 = e; }
    }
    float inv = 1.f / s;
    topi[t * 2] = i0; topi[t * 2 + 1] = i1;
    topw[t * 2] = v0 * inv; topw[t * 2 + 1] = v1 * inv;
  }
}

// ---- GEMM helpers: m97-swizzled stage + 16x16x32 MFMA compute ----
static __device__ __forceinline__ void stage_tile(
    unsigned short* Al, unsigned short* Bl,
    const unsigned short* __restrict__ Ab, const unsigned short* __restrict__ Btb,
    int Kd, int kb, int wid, int srow, int sslot) {
#pragma unroll
  for (int j = 0; j < 4; ++j) {
    const int c = wid * 4 + j;                 // chunk 0..15 (1KB each)
    const long long rowg = 8 * c + srow;
    gload_lds16(Ab  + rowg * Kd + kb + sslot * 8, &Al[c * 512]);
    gload_lds16(Btb + rowg * Kd + kb + sslot * 8, &Bl[c * 512]);
  }
}

static __device__ __forceinline__ void compute_tile(
    const unsigned short* Al, const unsigned short* Bl,
    int wr, int wc, int l15, int khi, int swz, f32x4 (&acc)[4][4]) {
#pragma unroll
  for (int kk = 0; kk < 2; ++kk) {
    bf16x8 af[4], bfv[4];
#pragma unroll
    for (int m = 0; m < 4; ++m)
      af[m] = *(const bf16x8*)&Al[(wr + m * 16 + l15) * 64 + (((kk * 4 + khi) ^ swz) << 3)];
#pragma unroll
    for (int n = 0; n < 4; ++n)
      bfv[n] = *(const bf16x8*)&Bl[(wc + n * 16 + l15) * 64 + (((kk * 4 + khi) ^ swz) << 3)];
#pragma unroll
    for (int m = 0; m < 4; ++m)
#pragma unroll
      for (int n = 0; n < 4; ++n)
        acc[m][n] = __builtin_amdgcn_mfma_f32_16x16x32_bf16(af[m], bfv[n], acc[m][n], 0, 0, 0);
  }
}

// double-buffered K-loop (catalog T3-minimum 2-phase): STAGE(next) -> vmcnt(8)
// -> barrier -> MFMA(cur) -> barrier. Raw barriers avoid the implicit full
// vmcnt(0) drain of __syncthreads; 8 loads/wave stay in flight across compute.
static __device__ __forceinline__ void gemm_mainloop_db(
    char* smem, const unsigned short* __restrict__ Ab,
    const unsigned short* __restrict__ Btb, int Kd, f32x4 (&acc)[4][4]) {
  unsigned short* A0 = (unsigned short*)smem;
  unsigned short* B0 = (unsigned short*)(smem + 16384);
  unsigned short* A1 = (unsigned short*)(smem + 32768);
  unsigned short* B1 = (unsigned short*)(smem + 49152);
  const int tid = threadIdx.x;
  const int lane = tid & 63;
  const int wid = tid >> 6;
  const int wr = (wid >> 1) * 64;
  const int wc = (wid & 1) * 64;
  const int l15 = lane & 15;
  const int khi = lane >> 4;
  const int swz = lane & 7;
  const int srow = lane >> 3;
  const int sslot = (lane & 7) ^ srow;

  const int nK = Kd >> 6;
  stage_tile(A0, B0, Ab, Btb, Kd, 0, wid, srow, sslot);
  int cur = 0;
  for (int kt = 0; kt < nK - 1; ++kt) {
    unsigned short* An = cur ? A0 : A1;
    unsigned short* Bn = cur ? B0 : B1;
    stage_tile(An, Bn, Ab, Btb, Kd, (kt + 1) << 6, wid, srow, sslot);
    asm volatile("s_waitcnt vmcnt(8)" ::: "memory");   // stage(kt) done (mine)
    __builtin_amdgcn_s_barrier();                      // everyone's stage(kt) done
    unsigned short* Ac = cur ? A1 : A0;
    unsigned short* Bc = cur ? B1 : B0;
    compute_tile(Ac, Bc, wr, wc, l15, khi, swz, acc);
    __builtin_amdgcn_s_barrier();                      // reads done before overwrite
    cur ^= 1;
  }
  asm volatile("s_waitcnt vmcnt(0)" ::: "memory");
  __builtin_amdgcn_s_barrier();
  compute_tile(cur ? A1 : A0, cur ? B1 : B0, wr, wc, l15, khi, swz, acc);
}

// ---------------- kernels ----------------

// fused pre-pass block order: router, W2 tiles, W1 tiles LAST (W1t hot in L2).
__global__ __launch_bounds__(256) void fused_pre_kernel(
    const float* __restrict__ x, const float* __restrict__ Wg,
    int* __restrict__ topi, float* __restrict__ topw,
    const float* __restrict__ W1, unsigned short* __restrict__ W1t,
    const float* __restrict__ W2, unsigned short* __restrict__ W2t,
    int nR, int nT2) {
  __shared__ __align__(16) float tile[64][33];
  const int bid = blockIdx.x;
  if (bid < nR) {
    router_body(x, Wg, topi, topw, bid);
  } else if (bid < nR + nT2) {
    // W2: Kd=Hm, N=Dm; layout (Dm/32) x (Hm/64) x NE
    int tb = bid - nR;
    int nb = tb % (Dm / 32);
    int rest = tb / (Dm / 32);
    int kb = rest % (Hm / 64);
    int e = rest / (Hm / 64);
    transpose_body(tile, W2, W2t, Hm, Dm, e, nb * 32, kb * 64);
  } else {
    // W1: Kd=Dm, N=Hm; layout (Hm/32) x (Dm/64) x NE
    int tb = bid - nR - nT2;
    int nb = tb % (Hm / 32);
    int rest = tb / (Hm / 32);
    int kb = rest % (Dm / 64);
    int e = rest / (Dm / 64);
    transpose_body(tile, W1, W1t, Dm, Hm, e, nb * 32, kb * 64);
  }
}

// dispatch: parallel slot-major multi-counter prefix scan (1 block x 1024)
__global__ __launch_bounds__(1024) void dispatch_scan_kernel(
    const int* __restrict__ topi, int* __restrict__ pos, int* __restrict__ within,
    int* __restrict__ cnt) {
  __shared__ unsigned long long sc0[1024];
  __shared__ unsigned long long sc1[1024];
  const int tid = threadIdx.x;
  int myE[8];
  unsigned long long w0 = 0, w1 = 0;
#pragma unroll
  for (int j = 0; j < 8; ++j) {
    int a = tid * 8 + j;
    int k = a >> 12;
    int t = a & (T - 1);
    int e = topi[t * 2 + k];
    myE[j] = e;
    unsigned long long inc = 1ULL << (16 * (e & 3));
    if (e < 4) w0 += inc; else w1 += inc;
  }
  const unsigned long long l0 = w0, l1 = w1;
  sc0[tid] = w0; sc1[tid] = w1;
  __syncthreads();
  for (int off = 1; off < 1024; off <<= 1) {
    unsigned long long a0 = 0, a1 = 0;
    if (tid >= off) { a0 = sc0[tid - off]; a1 = sc1[tid - off]; }
    __syncthreads();
    w0 += a0; w1 += a1;
    sc0[tid] = w0; sc1[tid] = w1;
    __syncthreads();
  }
  if (tid == 1023) {
#pragma unroll
    for (int e = 0; e < 4; ++e) {
      cnt[e]     = (int)((w0 >> (16 * e)) & 0xFFFF);
      cnt[e + 4] = (int)((w1 >> (16 * e)) & 0xFFFF);
    }
  }
  unsigned long long e0 = w0 - l0, e1 = w1 - l1;
#pragma unroll
  for (int j = 0; j < 8; ++j) {
    int a = tid * 8 + j;
    int e = myE[j];
    int sh = 16 * (e & 3);
    int p;
    if (e < 4) { p = (int)((e0 >> sh) & 0xFFFF); e0 += 1ULL << sh; }
    else       { p = (int)((e1 >> sh) & 0xFFFF); e1 += 1ULL << sh; }
    pos[a] = p;
    within[a] = (p < CAP) ? 1 : 0;
  }
}

// scatter accepted tokens -> buf[e][p] (bf16)
__global__ __launch_bounds__(256) void scatter_kernel(
    const float* __restrict__ x, const int* __restrict__ topi,
    const int* __restrict__ pos, const int* __restrict__ within,
    unsigned short* __restrict__ buf) {
  int a = blockIdx.x;
  if (!within[a]) return;
  int k = a >> 12, t = a & (T - 1);
  int e = topi[t * 2 + k];
  int p = pos[a];
  const float* src = x + (size_t)t * Dm;
  unsigned short* dst = buf + ((size_t)e * CP + p) * Dm;
  int i = threadIdx.x * 4;
  float4 v = *(const float4*)(src + i);
  ushort4 o;
  o.x = f2bf(v.x); o.y = f2bf(v.y); o.z = f2bf(v.z); o.w = f2bf(v.w);
  *(ushort4*)(dst + i) = o;
}

// GEMM1: h = gelu(buf @ W1t^T + b1)  [bf16 out], early-exit on expert count
__global__ __launch_bounds__(256) void gemm1_kernel(
    const unsigned short* __restrict__ buf, const unsigned short* __restrict__ W1t,
    const float* __restrict__ b1, unsigned short* __restrict__ h,
    const int* __restrict__ cnt) {
  __shared__ __align__(16) char smem[65536];
  const int e = blockIdx.x & 7;
  const int q = blockIdx.x >> 3;
  const int mb = q % (CP / 128);
  const int nb = q / (CP / 128);
  const int ce = min(cnt[e], CAP);
  if (mb * 128 >= ce) return;

  f32x4 acc[4][4];
#pragma unroll
  for (int m = 0; m < 4; ++m)
#pragma unroll
    for (int n = 0; n < 4; ++n) acc[m][n] = (f32x4){0.f, 0.f, 0.f, 0.f};

  gemm_mainloop_db(smem,
                   buf + ((long long)e * CP + mb * 128) * Dm,
                   W1t + ((long long)e * Hm + nb * 128) * Dm, Dm, acc);

  const int lane = threadIdx.x & 63;
  const int wid = threadIdx.x >> 6;
  const int wr = (wid >> 1) * 64;
  const int wc = (wid & 1) * 64;
  const int l15 = lane & 15;
  const int crow = (lane >> 4) * 4;
  const float* bias = b1 + (size_t)e * Hm;
  unsigned short* H = h + (size_t)e * CP * Hm;
#pragma unroll
  for (int m = 0; m < 4; ++m) {
#pragma unroll
    for (int n = 0; n < 4; ++n) {
      const long long col = (long long)nb * 128 + wc + n * 16 + l15;
      const float bvv = bias[col];
#pragma unroll
      for (int j = 0; j < 4; ++j) {
        const long long row = (long long)mb * 128 + wr + m * 16 + crow + j;
        float v = acc[m][n][j] + bvv;
        v = 0.5f * v * (1.f + erff(v * 0.70710678118654752f));
        H[row * Hm + col] = f2bf(v);
      }
    }
  }
}

// GEMM2: y = h @ W2t^T + b2  [bf16 out], early-exit on expert count
__global__ __launch_bounds__(256) void gemm2_kernel(
    const unsigned short* __restrict__ h, const unsigned short* __restrict__ W2t,
    const float* __restrict__ b2, unsigned short* __restrict__ y,
    const int* __restrict__ cnt) {
  __shared__ __align__(16) char smem[65536];
  const int e = blockIdx.x & 7;
  const int q = blockIdx.x >> 3;
  const int mb = q % (CP / 128);
  const int nb = q / (CP / 128);
  const int ce = min(cnt[e], CAP);
  if (mb * 128 >= ce) return;

  f32x4 acc[4][4];
#pragma unroll
  for (int m = 0; m < 4; ++m)
#pragma unroll
    for (int n = 0; n < 4; ++n) acc[m][n] = (f32x4){0.f, 0.f, 0.f, 0.f};

  gemm_mainloop_db(smem,
                   h + ((long long)e * CP + mb * 128) * Hm,
                   W2t + ((long long)e * Dm + nb * 128) * Hm, Hm, acc);

  const int lane = threadIdx.x & 63;
  const int wid = threadIdx.x >> 6;
  const int wr = (wid >> 1) * 64;
  const int wc = (wid & 1) * 64;
  const int l15 = lane & 15;
  const int crow = (lane >> 4) * 4;
  const float* bias = b2 + (size_t)e * Dm;
  unsigned short* Y = y + (size_t)e * CP * Dm;
#pragma unroll
  for (int m = 0; m < 4; ++m) {
#pragma unroll
    for (int n = 0; n < 4; ++n) {
      const long long col = (long long)nb * 128 + wc + n * 16 + l15;
      const float bvv = bias[col];
#pragma unroll
      for (int j = 0; j < 4; ++j) {
        const long long row = (long long)mb * 128 + wr + m * 16 + crow + j;
        Y[row * Dm + col] = f2bf(acc[m][n][j] + bvv);
      }
    }
  }
}

// combine: out[t] = sum_k w_k * y[e_k, p_k]   (y bf16)
__global__ __launch_bounds__(256) void combine_kernel(
    const unsigned short* __restrict__ y, const int* __restrict__ topi,
    const float* __restrict__ topw, const int* __restrict__ pos,
    const int* __restrict__ within, float* __restrict__ out) {
  int t = blockIdx.x;
  int i = threadIdx.x * 4;
  float4 r = {0.f, 0.f, 0.f, 0.f};
#pragma unroll
  for (int k = 0; k < 2; ++k) {
    int a = k * T + t;
    if (within[a]) {
      int e = topi[t * 2 + k];
      int p = pos[a];
      float w = topw[t * 2 + k];
      const unsigned short* yr = y + ((size_t)e * CP + p) * Dm + i;
      ushort4 v = *(const ushort4*)yr;
      r.x += w * bf2f(v.x); r.y += w * bf2f(v.y);
      r.z += w * bf2f(v.z); r.w += w * bf2f(v.w);
    }
  }
  *(float4*)(out + (size_t)t * Dm + i) = r;
}

// plain transpose (tight-memory fallback)
__global__ __launch_bounds__(256) void transpose_kernel(
    const float* __restrict__ W, unsigned short* __restrict__ Wt, int Kd, int N) {
  __shared__ __align__(16) float tile[64][33];
  transpose_body(tile, W, Wt, Kd, N, blockIdx.z, blockIdx.x * 32, blockIdx.y * 64);
}

extern "C" void kernel_launch(void* const* d_in, const int* in_sizes, int n_in,
                              void* d_out, int out_size, void* d_ws, size_t ws_size,
                              hipStream_t stream) {
  const float* x  = (const float*)d_in[0];
  const float* Wg = (const float*)d_in[1];
  const float* W1 = (const float*)d_in[2];
  const float* b1 = (const float*)d_in[3];
  const float* W2 = (const float*)d_in[4];
  const float* b2 = (const float*)d_in[5];
  float* out = (float*)d_out;

  char* ws = (char*)d_ws;
  const size_t sz_h   = (size_t)NE * CP * Hm * 2;   // 75.5 MB
  const size_t sz_buf = (size_t)NE * CP * Dm * 2;   // 18.9 MB (buf; later y bf16)
  const size_t sz_w   = (size_t)NE * Hm * Dm * 2;   // 67.1 MB
  const size_t sz_small = (size_t)2 * T * 4 * 4 + 64;
  const size_t need_full = sz_h + sz_buf + 2 * sz_w + sz_small;  // ~229 MB

  unsigned short* h   = (unsigned short*)ws;
  unsigned short* buf = (unsigned short*)(ws + sz_h);   // bf16 [E][CP][Dm]
  unsigned short* y   = buf;                            // bf16 y overwrites buf
  unsigned short* W1t = (unsigned short*)(ws + sz_h + sz_buf);
  const bool full = (ws_size >= need_full);
  unsigned short* W2t = full ? (W1t + sz_w / 2) : W1t;  // mid: shared slot
  char* smallp = ws + sz_h + sz_buf + (full ? 2 * sz_w : sz_w);
  int*   topi   = (int*)smallp;
  float* topw   = (float*)(topi + 2 * T);
  int*   pos    = (int*)(topw + 2 * T);
  int*   within = pos + 2 * T;
  int*   cnt    = within + 2 * T;

  const int nM = CP / 128;                    // 9
  const int nR = T / 4;                       // 1024 router blocks
  const int nT = (Hm / 32) * (Dm / 64) * NE;  // 16384 tiles per weight matrix
  const int nGemm1 = NE * nM * (Hm / 128);    // 2304
  const int nGemm2 = NE * nM * (Dm / 128);    // 576

  if (full) {
    // router + W2t + W1t(last) in one BW-bound pre-pass
    fused_pre_kernel<<<nR + 2 * nT, 256, 0, stream>>>(
        x, Wg, topi, topw, W1, W1t, W2, W2t, nR, nT);
    dispatch_scan_kernel<<<1, 1024, 0, stream>>>(topi, pos, within, cnt);
    scatter_kernel<<<2 * T, 256, 0, stream>>>(x, topi, pos, within, buf);
    gemm1_kernel<<<nGemm1, 256, 0, stream>>>(buf, W1t, b1, h, cnt);
    gemm2_kernel<<<nGemm2, 256, 0, stream>>>(h, W2t, b2, y, cnt);
  } else {
    // mid path (proven-fit 162 MB): W1t in pre-pass, W2t after GEMM1 (same slot)
    fused_pre_kernel<<<nR + nT, 256, 0, stream>>>(
        x, Wg, topi, topw, W1, W1t, W2, W2t, nR, 0);
    dispatch_scan_kernel<<<1, 1024, 0, stream>>>(topi, pos, within, cnt);
    scatter_kernel<<<2 * T, 256, 0, stream>>>(x, topi, pos, within, buf);
    gemm1_kernel<<<nGemm1, 256, 0, stream>>>(buf, W1t, b1, h, cnt);
    transpose_kernel<<<dim3(Dm / 32, Hm / 64, NE), 256, 0, stream>>>(W2, W2t, Hm, Dm);
    gemm2_kernel<<<nGemm2, 256, 0, stream>>>(h, W2t, b2, y, cnt);
  }

  combine_kernel<<<T, 256, 0, stream>>>(y, topi, topw, pos, within, out);
}